// Round 1
// 3058.115 us; speedup vs baseline: 1.4125x; 1.4125x over previous
//
#include <hip/hip_runtime.h>
#include <hip/hip_bf16.h>
#include <math.h>

// Problem constants
constexpr int B = 4, T = 256, D = 1024, H = 16, HD = 64, F = 4096, L = 6, V = 32000;
constexpr float EPS = 1e-6f;
constexpr int M_ROWS = B * T;     // 1024

typedef __hip_bfloat16 bf16;
typedef __bf16  bf16x8 __attribute__((ext_vector_type(8)));
typedef float   f32x4  __attribute__((ext_vector_type(4)));
typedef _Float16 h16;
typedef _Float16 h16x8 __attribute__((ext_vector_type(8)));

// flags layout (ints): [0]=do_skip, [1..4]=exited, [5..8]=newly, [9..12]=exl

__device__ inline void async_copy16(const void* g, void* l) {
    __builtin_amdgcn_global_load_lds(
        (const __attribute__((address_space(1))) void*)g,
        (__attribute__((address_space(3))) void*)l, 16, 0, 0);
}

// ---------------- init ----------------
__global__ void init_kernel(int* flags) {
    int t = threadIdx.x;
    if (t == 0) flags[0] = 0;
    if (t >= 1 && t <= 8) flags[t] = 0;
    if (t >= 9 && t <= 12) flags[t] = -1;
}

// ---------------- embedding ----------------
__global__ void embed_kernel(const int* __restrict__ ids, const float* __restrict__ emb,
                             float* __restrict__ x) {
    int row = blockIdx.x;
    int id = ids[row];
    ((float4*)(x + (size_t)row * D))[threadIdx.x] =
        ((const float4*)(emb + (size_t)id * D))[threadIdx.x];
}

// ---------------- transpose-convert fp32 [K][NS] -> bf16 [n*rs+ro][K] ----------------
__global__ __launch_bounds__(256) void convtrans_kernel(const float* __restrict__ src,
                                                        bf16* __restrict__ dst,
                                                        int K, int NS, int rs, int ro) {
    __shared__ float tile[64][65];
    int tid = threadIdx.x;
    int k0 = blockIdx.y * 64, n0 = blockIdx.x * 64;
    int cr = tid >> 6, cc = tid & 63;
#pragma unroll
    for (int p = 0; p < 16; p++)
        tile[p * 4 + cr][cc] = src[(size_t)(k0 + p * 4 + cr) * NS + n0 + cc];
    __syncthreads();
    int n = tid >> 4, k4 = (tid & 15) * 4;
#pragma unroll
    for (int p = 0; p < 4; p++) {
        int nn = p * 16 + n;
        union { ushort4 u4; bf16 h[4]; } cv;
        cv.h[0] = __float2bfloat16(tile[k4 + 0][nn]);
        cv.h[1] = __float2bfloat16(tile[k4 + 1][nn]);
        cv.h[2] = __float2bfloat16(tile[k4 + 2][nn]);
        cv.h[3] = __float2bfloat16(tile[k4 + 3][nn]);
        *(ushort4*)(dst + ((size_t)(n0 + nn) * rs + ro) * K + k0 + k4) = cv.u4;
    }
}

// ---------------- MFMA GEMM: C[M][ldc] (+)= A[M][K](bf16) @ BT[N][K](bf16)^T ----------------
// MODE 0: store fp32   MODE 1: accumulate fp32   MODE 2: silu-pair -> bf16 Cb[M][ldc/2]
// MODE 3: store f16 (Cb reinterpreted as _Float16*)
template<int MODE>
__global__ __launch_bounds__(256) void gemm_mfma(const bf16* __restrict__ A,
                                                 const bf16* __restrict__ BT,
                                                 float* __restrict__ C,
                                                 bf16* __restrict__ Cb,
                                                 int K, int ldc, const int* gate) {
    if (gate && *gate) return;
    __shared__ bf16 As[128 * 32];
    __shared__ bf16 Bs[128 * 32];
    int tid = threadIdx.x;
    int wave = tid >> 6, lane = tid & 63;
    int m0 = blockIdx.y * 128, n0 = blockIdx.x * 128;
    int srow = lane >> 2, scol = (lane & 3) * 8;
    int wm = wave >> 1, wn = wave & 1;
    int rowbase = wm * 64, colbase = wn * 64;
    int fm = lane & 15, quad = lane >> 4;
    f32x4 acc[4][4] = {};
    for (int k0 = 0; k0 < K; k0 += 32) {
#pragma unroll
        for (int r = 0; r < 2; r++) {
            int c = wave * 2 + r;
            int arow = c * 16 + srow;
            async_copy16(A + (size_t)(m0 + arow) * K + k0 + scol, &As[c * 512 + lane * 8]);
            async_copy16(BT + (size_t)(n0 + arow) * K + k0 + scol, &Bs[c * 512 + lane * 8]);
        }
        __syncthreads();
        bf16x8 af[4], bfr[4];
#pragma unroll
        for (int i = 0; i < 4; i++)
            af[i] = *(const bf16x8*)&As[(rowbase + i * 16 + fm) * 32 + quad * 8];
#pragma unroll
        for (int j = 0; j < 4; j++)
            bfr[j] = *(const bf16x8*)&Bs[(colbase + j * 16 + fm) * 32 + quad * 8];
#pragma unroll
        for (int i = 0; i < 4; i++)
#pragma unroll
            for (int j = 0; j < 4; j++)
                acc[i][j] = __builtin_amdgcn_mfma_f32_16x16x32_bf16(af[i], bfr[j], acc[i][j], 0, 0, 0);
        __syncthreads();
    }
#pragma unroll
    for (int i = 0; i < 4; i++) {
        int row = m0 + rowbase + i * 16 + quad * 4;
#pragma unroll
        for (int j = 0; j < 4; j++) {
            int col = n0 + colbase + j * 16 + fm;
#pragma unroll
            for (int r = 0; r < 4; r++) {
                float vv = acc[i][j][r];
                if (MODE == 0) {
                    C[(size_t)(row + r) * ldc + col] = vv;
                } else if (MODE == 1) {
                    C[(size_t)(row + r) * ldc + col] += vv;
                } else if (MODE == 3) {
                    ((_Float16*)Cb)[(size_t)(row + r) * ldc + col] = (_Float16)vv;
                } else {
                    float g = __shfl_xor(vv, 1, 64);   // neighbor holds the w3 (odd-col) value
                    if ((lane & 1) == 0) {
                        float s = vv / (1.f + expf(-vv)) * g;
                        Cb[(size_t)(row + r) * (ldc >> 1) + (col >> 1)] = __float2bfloat16(s);
                    }
                }
            }
        }
    }
}

// ---------------- skip decision (x BEFORE block) ----------------
__global__ void skip_kernel(const float* __restrict__ x, const float* __restrict__ sw,
                            const float* __restrict__ sb, int* flags, int li) {
    __shared__ float red[256];
    __shared__ float dots[B];
    int tid = threadIdx.x;
    for (int b = 0; b < B; b++) {
        const float* xr = x + ((size_t)(b * T + T - 1)) * D;
        float s = 0.f;
        for (int d = tid; d < D; d += 256) s += xr[d] * sw[d];
        red[tid] = s; __syncthreads();
        for (int off = 128; off > 0; off >>= 1) {
            if (tid < off) red[tid] += red[tid + off];
            __syncthreads();
        }
        if (tid == 0) dots[b] = red[0];
        __syncthreads();
    }
    if (tid == 0) {
        float cnt = 0.f, sum = 0.f;
        for (int b = 0; b < B; b++) {
            float p = 1.f / (1.f + expf(-(dots[b] + sb[li])));
            if (!flags[1 + b]) { cnt += 1.f; sum += p; }
        }
        float mean = sum / fmaxf(cnt, 1.f);
        flags[0] = (li >= 1 && cnt > 0.f && mean < 0.1f) ? 1 : 0;
    }
}

// ---------------- rmsnorm -> bf16 ----------------
__global__ void rmsnorm_bf16_kernel(const float* __restrict__ x, const float* __restrict__ w,
                                    bf16* __restrict__ out, const int* gate) {
    if (gate && *gate) return;
    int row = blockIdx.x;
    const float* xr = x + (size_t)row * D;
    __shared__ float red[256];
    int tid = threadIdx.x;
    float s = 0.f;
    for (int d = tid; d < D; d += 256) { float vv = xr[d]; s += vv * vv; }
    red[tid] = s; __syncthreads();
    for (int off = 128; off > 0; off >>= 1) {
        if (tid < off) red[tid] += red[tid + off];
        __syncthreads();
    }
    float r = rsqrtf(red[0] / (float)D + EPS);
    for (int d = tid; d < D; d += 256)
        out[(size_t)row * D + d] = __float2bfloat16(xr[d] * w[d] * r);
}

// ---------------- RoPE on fused qkv f16 buffer ----------------
__global__ void rope_kernel(h16* __restrict__ qkv, const int* gate) {
    if (*gate) return;
    int idx = blockIdx.x * 256 + threadIdx.x;   // B*T*H*32 items
    int i = idx & 31; idx >>= 5;
    int h = idx & (H - 1); idx >>= 4;
    int t = idx & (T - 1); idx >>= 8;
    int b = idx;
    float inv = exp2f(-(float)i / 32.f * 13.287712379549449f);
    float f = (float)t * inv;
    float c = cosf(f), s = sinf(f);
    size_t base = (size_t)(b * T + t) * 3072 + h * 64;
    float q1 = (float)qkv[base + i], q2 = (float)qkv[base + 32 + i];
    qkv[base + i]      = (h16)(q1 * c - q2 * s);
    qkv[base + 32 + i] = (h16)(q1 * s + q2 * c);
    size_t kb = base + 1024;
    float k1 = (float)qkv[kb + i], k2 = (float)qkv[kb + 32 + i];
    qkv[kb + i]      = (h16)(k1 * c - k2 * s);
    qkv[kb + 32 + i] = (h16)(k1 * s + k2 * c);
}

// ---------------- MFMA flash attention ----------------
// grid: B*H*4 blocks (qt = 64-row q-tile), 256 threads (4 waves x 16 q-rows each)
__global__ __launch_bounds__(256) void attn_mfma(const h16* __restrict__ qkv,
                                                 bf16* __restrict__ o, const int* gate) {
    if (*gate) return;
    int blk = blockIdx.x;
    int qt = blk & 3;
    int h = (blk >> 2) & (H - 1);
    int b = blk >> 6;
    int q0 = qt * 64;
    int tid = threadIdx.x;
    int wave = tid >> 6, lane = tid & 63;
    int fm = lane & 15, quad = lane >> 4;

    __shared__ h16 Qs[64 * 64];       // [row][d], chunk-swizzled by (row&7)
    __shared__ h16 Ks[64 * 64];       // [j][d],  chunk-swizzled by (j&7)
    __shared__ h16 Vt[64 * 64];       // [d][j],  chunk-swizzled by (d&7)^((d>>4)&3)
    __shared__ h16 Ps[4 * 16 * 64];   // per-wave P tile, swizzled by (row&7)
    h16* Pw = Ps + wave * 1024;

    // stage Q (async; inverse-swizzled global source, linear LDS dest)
#pragma unroll
    for (int c = 0; c < 2; c++) {
        int chunk = (wave * 2 + c) * 64 + lane;
        int row = chunk >> 3, c16 = chunk & 7;
        const h16* g = qkv + (size_t)(b * T + q0 + row) * 3072 + h * 64 + ((c16 ^ (row & 7)) << 3);
        async_copy16(g, &Qs[chunk << 3]);
    }

    float mrow[4] = { -1e30f, -1e30f, -1e30f, -1e30f };
    float lrow[4] = { 0.f, 0.f, 0.f, 0.f };
    f32x4 oacc[4] = {};

    for (int kt = 0; kt <= qt; kt++) {
        // stage K tile (async, same swizzle)
#pragma unroll
        for (int c = 0; c < 2; c++) {
            int chunk = (wave * 2 + c) * 64 + lane;
            int row = chunk >> 3, c16 = chunk & 7;
            const h16* g = qkv + (size_t)(b * T + kt * 64 + row) * 3072 + 1024 + h * 64 + ((c16 ^ (row & 7)) << 3);
            async_copy16(g, &Ks[chunk << 3]);
        }
        // stage V transposed (reg-staged, swizzled b16 writes)
        {
            int j = tid >> 2, d0 = (tid & 3) << 4;
            const h16* gv = qkv + (size_t)(b * T + kt * 64 + j) * 3072 + 2048 + h * 64 + d0;
            union { float4 f[2]; h16 v[16]; } u;
            u.f[0] = *(const float4*)gv;
            u.f[1] = *(const float4*)(gv + 8);
#pragma unroll
            for (int i = 0; i < 16; i++) {
                int d = d0 + i;
                int swz = (d & 7) ^ ((d >> 4) & 3);
                Vt[d * 64 + (((j >> 3) ^ swz) << 3) + (j & 7)] = u.v[i];
            }
        }
        __syncthreads();

        // S = Q K^T (wave owns rows wave*16..+15; full 64 cols of the tile)
        h16x8 aq[2], bk[2][4];
#pragma unroll
        for (int s = 0; s < 2; s++) {
            int row = wave * 16 + fm;
            aq[s] = *(const h16x8*)&Qs[row * 64 + ((((s << 2) | quad) ^ (row & 7)) << 3)];
#pragma unroll
            for (int nt = 0; nt < 4; nt++) {
                int j = nt * 16 + fm;
                bk[s][nt] = *(const h16x8*)&Ks[j * 64 + ((((s << 2) | quad) ^ (j & 7)) << 3)];
            }
        }
        f32x4 sacc[4] = {};
#pragma unroll
        for (int s = 0; s < 2; s++)
#pragma unroll
            for (int nt = 0; nt < 4; nt++)
                sacc[nt] = __builtin_amdgcn_mfma_f32_16x16x32_f16(aq[s], bk[s][nt], sacc[nt], 0, 0, 0);

        // scale + causal mask (only diagonal tile can mask)
        bool diag = (kt == qt);
        int rbase = q0 + wave * 16 + quad * 4;
#pragma unroll
        for (int nt = 0; nt < 4; nt++) {
            int jg = kt * 64 + nt * 16 + fm;
#pragma unroll
            for (int r = 0; r < 4; r++) {
                float sv = sacc[nt][r] * 0.125f;
                if (diag && jg > rbase + r) sv = -1e30f;
                sacc[nt][r] = sv;
            }
        }
        // online softmax: row m = quad*4+r, spread over 16 fm-lanes x 4 nt
#pragma unroll
        for (int r = 0; r < 4; r++) {
            float vm = fmaxf(fmaxf(sacc[0][r], sacc[1][r]), fmaxf(sacc[2][r], sacc[3][r]));
            vm = fmaxf(vm, __shfl_xor(vm, 1, 64));
            vm = fmaxf(vm, __shfl_xor(vm, 2, 64));
            vm = fmaxf(vm, __shfl_xor(vm, 4, 64));
            vm = fmaxf(vm, __shfl_xor(vm, 8, 64));
            float mnew = fmaxf(mrow[r], vm);
            float sc = expf(mrow[r] - mnew);
            float ps = 0.f;
#pragma unroll
            for (int nt = 0; nt < 4; nt++) {
                float p = expf(sacc[nt][r] - mnew);
                sacc[nt][r] = p;
                ps += p;
            }
            ps += __shfl_xor(ps, 1, 64);
            ps += __shfl_xor(ps, 2, 64);
            ps += __shfl_xor(ps, 4, 64);
            ps += __shfl_xor(ps, 8, 64);
            lrow[r] = lrow[r] * sc + ps;
            mrow[r] = mnew;
#pragma unroll
            for (int dt = 0; dt < 4; dt++) oacc[dt][r] *= sc;
        }
        // write P tile (f16) to wave-private LDS
#pragma unroll
        for (int nt = 0; nt < 4; nt++) {
            int col = nt * 16 + fm;
            int chunk = col >> 3, wi = col & 7;
#pragma unroll
            for (int r = 0; r < 4; r++) {
                int rowl = quad * 4 + r;
                Pw[rowl * 64 + ((chunk ^ (rowl & 7)) << 3) + wi] = (h16)sacc[nt][r];
            }
        }
        __syncthreads();
        // O += P V
#pragma unroll
        for (int s = 0; s < 2; s++) {
            h16x8 ap = *(const h16x8*)&Pw[fm * 64 + ((((s << 2) | quad) ^ (fm & 7)) << 3)];
#pragma unroll
            for (int dt = 0; dt < 4; dt++) {
                int d = dt * 16 + fm;
                int swz = (d & 7) ^ ((d >> 4) & 3);
                h16x8 bv = *(const h16x8*)&Vt[d * 64 + ((((s << 2) | quad) ^ swz) << 3)];
                oacc[dt] = __builtin_amdgcn_mfma_f32_16x16x32_f16(ap, bv, oacc[dt], 0, 0, 0);
            }
        }
        __syncthreads();
    }
    // normalize + write O (bf16)
#pragma unroll
    for (int r = 0; r < 4; r++) {
        float invl = 1.f / lrow[r];
        int trow = b * T + q0 + wave * 16 + quad * 4 + r;
#pragma unroll
        for (int dt = 0; dt < 4; dt++)
            o[(size_t)trow * 1024 + h * 64 + dt * 16 + fm] = __float2bfloat16(oacc[dt][r] * invl);
    }
}

// ---------------- rmsnorm of last token only -> fp32 hl[B,D] ----------------
__global__ void hlast_kernel(const float* __restrict__ x, const float* __restrict__ fn,
                             float* __restrict__ hl, const int* gate) {
    if (*gate) return;
    int b = blockIdx.x;
    const float* xr = x + ((size_t)(b * T + T - 1)) * D;
    __shared__ float red[256];
    int tid = threadIdx.x;
    float s = 0.f;
    for (int d = tid; d < D; d += 256) { float vv = xr[d]; s += vv * vv; }
    red[tid] = s; __syncthreads();
    for (int off = 128; off > 0; off >>= 1) {
        if (tid < off) red[tid] += red[tid + off];
        __syncthreads();
    }
    float r = rsqrtf(red[0] / (float)D + EPS);
    for (int d = tid; d < D; d += 256) hl[b * D + d] = xr[d] * fn[d] * r;
}

// ---------------- last-token logits partials (fp32 lm_head, online softmax) ----------------
__global__ __launch_bounds__(256) void logits_partial_kernel(const float* __restrict__ hl,
                                                             const float* __restrict__ lm,
                                                             float* __restrict__ partial,
                                                             const int* gate) {
    if (*gate) return;
    __shared__ float hls[B * D];
    int tid = threadIdx.x;
    for (int i = tid; i < B * D; i += 256) hls[i] = hl[i];
    __syncthreads();
    int v0 = blockIdx.x * 256 + tid;
    float a0 = 0.f, a1 = 0.f, a2 = 0.f, a3 = 0.f;
    for (int d = 0; d < D; d++) {
        float w = lm[(size_t)d * V + v0];
        a0 += hls[d] * w;
        a1 += hls[D + d] * w;
        a2 += hls[2 * D + d] * w;
        a3 += hls[3 * D + d] * w;
    }
    float l[B] = { a0, a1, a2, a3 };
    __shared__ float rm[256], rs[256];
    for (int b = 0; b < B; b++) {
        rm[tid] = l[b]; rs[tid] = 1.f; __syncthreads();
        for (int off = 128; off > 0; off >>= 1) {
            if (tid < off) {
                float m1 = rm[tid], s1 = rs[tid], m2 = rm[tid + off], s2 = rs[tid + off];
                float mm = fmaxf(m1, m2);
                rs[tid] = s1 * expf(m1 - mm) + s2 * expf(m2 - mm);
                rm[tid] = mm;
            }
            __syncthreads();
        }
        if (tid == 0) {
            partial[((size_t)blockIdx.x * B + b) * 2]     = rm[0];
            partial[((size_t)blockIdx.x * B + b) * 2 + 1] = rs[0];
        }
        __syncthreads();
    }
}

// ---------------- exit decision ----------------
__global__ void decide_kernel(const float* __restrict__ x, const float* __restrict__ ew,
                              const float* __restrict__ eb, const float* __restrict__ partial,
                              int* flags, int li) {
    __shared__ float red[256];
    __shared__ float dots[B];
    int tid = threadIdx.x;
    int doSkip = flags[0];
    for (int b = 0; b < B; b++) {
        const float* xr = x + ((size_t)(b * T + T - 1)) * D;
        float s = 0.f;
        for (int d = tid; d < D; d += 256) s += xr[d] * ew[d];
        red[tid] = s; __syncthreads();
        for (int off = 128; off > 0; off >>= 1) {
            if (tid < off) red[tid] += red[tid + off];
            __syncthreads();
        }
        if (tid == 0) dots[b] = red[0];
        __syncthreads();
    }
    if (tid == 0) {
        for (int b = 0; b < B; b++) {
            int newly = 0;
            if (!doSkip) {
                float m = -1e30f, s = 0.f;
                for (int g = 0; g < 125; g++) {
                    float mg = partial[((size_t)g * B + b) * 2];
                    float sg = partial[((size_t)g * B + b) * 2 + 1];
                    float mn = fmaxf(m, mg);
                    s = s * expf(m - mn) + sg * expf(mg - mn);
                    m = mn;
                }
                float conf = 1.f / s;
                float ep = 1.f / (1.f + expf(-(dots[b] + eb[li])));
                int should = (conf > 0.9f) || (ep > 0.9f);
                if (should && !flags[1 + b]) newly = 1;
            }
            flags[5 + b] = newly;
            if (newly) { flags[1 + b] = 1; flags[9 + b] = li; }
        }
    }
}

// ---------------- capture x for newly-exited batches ----------------
__global__ void capture_kernel(const float* __restrict__ x, float* __restrict__ xcap,
                               const int* flags) {
    int row = blockIdx.x;
    int b = row >> 8;
    if (!flags[5 + b]) return;
    ((float4*)(xcap + (size_t)row * D))[threadIdx.x] =
        ((const float4*)(x + (size_t)row * D))[threadIdx.x];
}

// ---------------- finalize never-exited batches ----------------
__global__ void finalize_kernel(const float* __restrict__ x, float* __restrict__ xcap,
                                int* flags) {
    int row = blockIdx.x;
    int b = row >> 8;
    if (flags[1 + b]) return;
    ((float4*)(xcap + (size_t)row * D))[threadIdx.x] =
        ((const float4*)(x + (size_t)row * D))[threadIdx.x];
    if ((row & (T - 1)) == 0 && threadIdx.x == 0) flags[9 + b] = L - 1;
}

// ---------------- write exl as floats after logits ----------------
__global__ void writeexl_kernel(float* __restrict__ out, const int* flags) {
    int b = threadIdx.x;
    if (b < B) out[(size_t)B * T * V + b] = (float)flags[9 + b];
}

extern "C" void kernel_launch(void* const* d_in, const int* in_sizes, int n_in,
                              void* d_out, int out_size, void* d_ws, size_t ws_size,
                              hipStream_t stream) {
    const int*   ids = (const int*)d_in[0];
    const float* emb = (const float*)d_in[1];
    const float* wq  = (const float*)d_in[2];
    const float* wk  = (const float*)d_in[3];
    const float* wv  = (const float*)d_in[4];
    const float* wo  = (const float*)d_in[5];
    const float* w1  = (const float*)d_in[6];
    const float* w2  = (const float*)d_in[7];
    const float* w3  = (const float*)d_in[8];
    const float* n1  = (const float*)d_in[9];
    const float* n2  = (const float*)d_in[10];
    const float* fn  = (const float*)d_in[11];
    const float* lm  = (const float*)d_in[12];
    const float* exw = (const float*)d_in[13];
    const float* exb = (const float*)d_in[14];
    const float* skw = (const float*)d_in[15];
    const float* skb = (const float*)d_in[16];

    char* base = (char*)d_ws;
    float* xB    = (float*)(base + 0x00000000);          // 4 MB
    h16*   qkvH  = (h16*)  (base + 0x00400000);          // 6 MB f16 [M][3072]
    float* xcap  = (float*)(base + 0x01000000);          // 4 MB
    bf16*  a2B   = (bf16*) (base + 0x01400000);          // 8 MB  [M][4096]
    bf16*  wqkvT = (bf16*) (base + 0x01C00000);          // 6 MB  [3072][1024]
    bf16*  w13T  = (bf16*) (base + 0x02200000);          // 16 MB [8192][1024] interleaved u/g
    bf16*  w2T   = (bf16*) (base + 0x03200000);          // 8 MB  [1024][4096]
    bf16*  woT   = (bf16*) (base + 0x03A00000);          // 2 MB  [1024][1024]
    bf16*  hB    = (bf16*) (base + 0x03C00000);          // 2 MB  [M][1024]
    bf16*  oB    = (bf16*) (base + 0x03E00000);          // 2 MB  [M][1024]
    bf16*  hfin  = (bf16*) (base + 0x04000000);          // 2 MB  [M][1024]
    bf16*  lmTc  = (bf16*) (base + 0x04200000);          // 6.25 MB [3200][1024]
    float* hl    = (float*)(base + 0x04900000);          // 16 KB
    float* part  = (float*)(base + 0x04904000);          // 4 KB
    int*   flags = (int*)  (base + 0x04905000);

    init_kernel<<<1, 64, 0, stream>>>(flags);
    embed_kernel<<<M_ROWS, 256, 0, stream>>>(ids, emb, xB);

    for (int li = 0; li < L; li++) {
        const int* gate = flags;
        size_t wOffDD = (size_t)li * D * D;
        size_t wOffDF = (size_t)li * D * F;
        // weight conversions (transposed bf16, per-layer buffers)
        convtrans_kernel<<<dim3(16, 16), 256, 0, stream>>>(wq + wOffDD, wqkvT, 1024, 1024, 1, 0);
        convtrans_kernel<<<dim3(16, 16), 256, 0, stream>>>(wk + wOffDD, wqkvT, 1024, 1024, 1, 1024);
        convtrans_kernel<<<dim3(16, 16), 256, 0, stream>>>(wv + wOffDD, wqkvT, 1024, 1024, 1, 2048);
        convtrans_kernel<<<dim3(16, 16), 256, 0, stream>>>(wo + wOffDD, woT,   1024, 1024, 1, 0);
        convtrans_kernel<<<dim3(64, 16), 256, 0, stream>>>(w1 + wOffDF, w13T,  1024, 4096, 2, 0);
        convtrans_kernel<<<dim3(64, 16), 256, 0, stream>>>(w3 + wOffDF, w13T,  1024, 4096, 2, 1);
        convtrans_kernel<<<dim3(16, 64), 256, 0, stream>>>(w2 + wOffDF, w2T,   4096, 1024, 1, 0);

        skip_kernel<<<1, 256, 0, stream>>>(xB, skw + (size_t)li * D, skb, flags, li);
        rmsnorm_bf16_kernel<<<M_ROWS, 256, 0, stream>>>(xB, n1 + (size_t)li * D, hB, gate);
        gemm_mfma<3><<<dim3(24, 8), 256, 0, stream>>>(hB, wqkvT, nullptr, (bf16*)qkvH, 1024, 3072, gate);
        rope_kernel<<<(B * T * H * 32) / 256, 256, 0, stream>>>(qkvH, gate);
        attn_mfma<<<B * H * 4, 256, 0, stream>>>(qkvH, oB, gate);
        gemm_mfma<1><<<dim3(8, 8), 256, 0, stream>>>(oB, woT, xB, nullptr, 1024, 1024, gate);
        rmsnorm_bf16_kernel<<<M_ROWS, 256, 0, stream>>>(xB, n2 + (size_t)li * D, hB, gate);
        gemm_mfma<2><<<dim3(64, 8), 256, 0, stream>>>(hB, w13T, nullptr, a2B, 1024, 8192, gate);
        gemm_mfma<1><<<dim3(8, 8), 256, 0, stream>>>(a2B, w2T, xB, nullptr, 4096, 1024, gate);

        hlast_kernel<<<B, 256, 0, stream>>>(xB, fn, hl, gate);
        logits_partial_kernel<<<125, 256, 0, stream>>>(hl, lm, part, gate);
        decide_kernel<<<1, 256, 0, stream>>>(xB, exw + (size_t)li * D, exb, part, flags, li);
        capture_kernel<<<M_ROWS, 256, 0, stream>>>(xB, xcap, flags);
    }

    finalize_kernel<<<M_ROWS, 256, 0, stream>>>(xB, xcap, flags);
    rmsnorm_bf16_kernel<<<M_ROWS, 256, 0, stream>>>(xcap, fn, hfin, nullptr);
    // final logits: 10 chunks of 3200 cols, transpose-convert lm chunk then MFMA GEMM
    for (int c = 0; c < 10; c++) {
        convtrans_kernel<<<dim3(50, 16), 256, 0, stream>>>(lm + c * 3200, lmTc, 1024, V, 1, 0);
        gemm_mfma<0><<<dim3(25, 8), 256, 0, stream>>>(hfin, lmTc, (float*)d_out + c * 3200,
                                                      nullptr, 1024, V, nullptr);
    }
    writeexl_kernel<<<1, 64, 0, stream>>>((float*)d_out, flags);
}